// Round 15
// baseline (313.059 us; speedup 1.0000x reference)
//
#include <hip/hip_runtime.h>
#include <math.h>

#define T_DIM 2048
#define C_DIM 1024
#define H_DIM 16
#define HD 64
#define TOPK_K 64
#define QTILE 8
#define LCAP 128

typedef __attribute__((ext_vector_type(8))) __bf16 bf16x8;
typedef __attribute__((ext_vector_type(4))) float f32x4;

__device__ __forceinline__ unsigned short bf16rn(float x) {
  unsigned u = __float_as_uint(x);
  return (unsigned short)((u + 0x7FFFu + ((u >> 16) & 1u)) >> 16);
}
__device__ __forceinline__ unsigned f2u(float f) {
  unsigned u = __float_as_uint(f);
  return (u & 0x80000000u) ? ~u : (u | 0x80000000u);
}
__device__ __forceinline__ float u2f(unsigned u) {
  unsigned v = (u & 0x80000000u) ? (u & 0x7FFFFFFFu) : ~u;
  return __uint_as_float(v);
}
__device__ __forceinline__ bf16x8 ld_frag(const uint4* p) {
  uint4 u = *p;
  return __builtin_bit_cast(bf16x8, u);
}
#define PAD_KEY 0x007FFFFFu   // f2u(-INF); real raw scores always exceed this

// ------- fused fp32 -> frag-global bf16 hi/lo converter + rope table --------
__global__ __launch_bounds__(256) void convert_all_kernel(
    const float* __restrict__ x, const float* __restrict__ wa,
    const float* __restrict__ wg, const float* __restrict__ wp,
    unsigned short* __restrict__ xh, unsigned short* __restrict__ xl,
    unsigned short* __restrict__ wqgh, unsigned short* __restrict__ wqgl,
    unsigned short* __restrict__ wph, unsigned short* __restrict__ wpl,
    float2* __restrict__ tab)
{
  const int tid = blockIdx.x * 256 + threadIdx.x;
  const int k8 = tid & 127, r = tid >> 7;
  if (r >= 7168) {   // rope sincos table tail: 512 r-slots x 128 = 65536
    const int e = ((r - 7168) << 7) | k8;
    const int t = e >> 5, d = e & 31;
    double invf = exp(-(double)d * (log(10000.0) / 32.0));
    double ang = (double)t * invf;
    tab[e] = make_float2((float)cos(ang), (float)sin(ang));
    return;
  }
  const float* src;
  unsigned short *Dh, *Dl;
  int srow, drow;
  if (r < 2048)      { src = x;  Dh = xh;   Dl = xl;   srow = r;        drow = r; }
  else if (r < 5120) { src = wa; Dh = wqgh; Dl = wqgl; srow = r - 2048; drow = r - 2048; }
  else if (r < 6144) { src = wg; Dh = wqgh; Dl = wqgl; srow = r - 5120; drow = r - 2048; }
  else               { src = wp; Dh = wph;  Dl = wpl;  srow = r - 6144; drow = r - 6144; }
  const float* s = src + ((size_t)srow << 10) + (k8 << 3);
  float4 a = *(const float4*)s;
  float4 b = *(const float4*)(s + 4);
  float xs[8] = {a.x, a.y, a.z, a.w, b.x, b.y, b.z, b.w};
  unsigned hi[8], lo[8];
#pragma unroll
  for (int jj = 0; jj < 8; ++jj) {
    unsigned short hb = bf16rn(xs[jj]);
    hi[jj] = hb;
    lo[jj] = bf16rn(xs[jj] - __uint_as_float((unsigned)hb << 16));
  }
  const int t16 = drow >> 4, rr = drow & 15, kc = k8 >> 2, kq = k8 & 3;
  const size_t elem = (((size_t)(t16 * 32 + kc)) * 64 + ((kq << 4) | rr)) * 8;
  uint4 vh, vl;
  vh.x = hi[0] | (hi[1] << 16); vh.y = hi[2] | (hi[3] << 16);
  vh.z = hi[4] | (hi[5] << 16); vh.w = hi[6] | (hi[7] << 16);
  vl.x = lo[0] | (lo[1] << 16); vl.y = lo[2] | (lo[3] << 16);
  vl.z = lo[4] | (lo[5] << 16); vl.w = lo[6] | (lo[7] << 16);
  *(uint4*)(Dh + elem) = vh;
  *(uint4*)(Dl + elem) = vl;
}

// ---------------- split-bf16 MFMA GEMM machinery ----------------
__device__ __forceinline__ void gld_lds16(const unsigned short* g, unsigned short* l) {
  __builtin_amdgcn_global_load_lds(
      (const __attribute__((address_space(1))) unsigned int*)g,
      (__attribute__((address_space(3))) unsigned int*)l, 16, 0, 0);
}

// qkv+gate GEMM, 128x128 tiles: grid (32, 16), 512 threads (8 waves), 2/CU.
// q/k blocks (bx<16) fuse the RoPE + attention-frag hi/lo split into the
// epilogue (deletes prep_frag + 32 MB of q/k f32 round-trip).
__global__ __launch_bounds__(512, 4) void mgemm_qkvg_kernel(
    const unsigned short* __restrict__ Ah, const unsigned short* __restrict__ Al,
    const unsigned short* __restrict__ Bh, const unsigned short* __restrict__ Bl,
    float* __restrict__ Cq, float* __restrict__ Ck, float* __restrict__ Cv,
    float* __restrict__ Cg, const float2* __restrict__ tab)
{
  __shared__ __align__(16) char smemAll[34816];  // As 16K | Bs 16K; rope 33.8K overlay
  unsigned short* As = (unsigned short*)smemAll;
  unsigned short* Bs = (unsigned short*)(smemAll + 16384);
  const int tid = threadIdx.x, lane = tid & 63, w = tid >> 6;
  const int mt0 = blockIdx.y << 3;   // 8 tiles16 of A rows
  const int nt0 = blockIdx.x << 3;   // 8 tiles16 of B rows

  f32x4 acc[8];
#pragma unroll
  for (int j = 0; j < 8; ++j) acc[j] = (f32x4){0.f, 0.f, 0.f, 0.f};

  for (int kc = 0; kc < 32; ++kc) {
#pragma unroll
    for (int li = 0; li < 4; ++li) {
      const int gi = (w << 2) + li;        // 0..31
      const int isB = gi >= 16;
      const int gb = gi & 15;
      const int t  = gb & 7;
      const int hl = gb >> 3;
      const unsigned short* gbase = isB ? (hl ? Bl : Bh) : (hl ? Al : Ah);
      const int tg = (isB ? nt0 : mt0) + t;
      const unsigned short* g = gbase + (((size_t)(tg * 32 + kc) << 6) + lane) * 8;
      unsigned short* l = (isB ? Bs : As) + hl * 4096 + t * 512;
      gld_lds16(g, l);
    }
    __syncthreads();
    bf16x8 ah = *(const bf16x8*)&As[w * 512 + lane * 8];
    bf16x8 al = *(const bf16x8*)&As[4096 + w * 512 + lane * 8];
#pragma unroll
    for (int j = 0; j < 8; ++j) {
      bf16x8 bh = *(const bf16x8*)&Bs[j * 512 + lane * 8];
      bf16x8 bl = *(const bf16x8*)&Bs[4096 + j * 512 + lane * 8];
      acc[j] = __builtin_amdgcn_mfma_f32_16x16x32_bf16(ah, bh, acc[j], 0, 0, 0);
      acc[j] = __builtin_amdgcn_mfma_f32_16x16x32_bf16(ah, bl, acc[j], 0, 0, 0);
      acc[j] = __builtin_amdgcn_mfma_f32_16x16x32_bf16(al, bh, acc[j], 0, 0, 0);
    }
    __syncthreads();
  }

  const int col = lane & 15, quad = lane >> 4;
  const int bxx = blockIdx.x;
  if (bxx < 16) {
    // ---- fused RoPE + frag-split for q (bxx<8) / k (bxx>=8) ----
    float* W = (float*)smemAll + w * (16 * 66);   // wave-private; As/Bs dead
    float* qkbuf = (bxx < 8) ? Cq : Ck;
    const int hb = (bxx & 7) << 1;                // head pair base
    const int t16 = (blockIdx.y << 3) + w;        // this wave's frag tile16
    const int t = (t16 << 4) + col;               // row on the read side (nr=col)
    const float2* tb = tab + t * 32 + (quad << 3);
#pragma unroll
    for (int jh = 0; jh < 2; ++jh) {
      // scatter this head's raw acc into the wave's LDS tile [row][d]
#pragma unroll
      for (int j2 = 0; j2 < 4; ++j2)
#pragma unroll
        for (int reg = 0; reg < 4; ++reg)
          W[(quad * 4 + reg) * 66 + (j2 << 4) + col] = acc[(jh << 2) + j2][reg];
      // read back in frag order (lane -> row=col, d0=quad*8) and run
      // prep_frag's exact RoPE + hi/lo split
      const float* rowp = W + col * 66;
      float x0[8], x1[8];
#pragma unroll
      for (int jj = 0; jj < 8; ++jj) {
        x0[jj] = rowp[(quad << 3) + jj];
        x1[jj] = rowp[32 + (quad << 3) + jj];
      }
      unsigned short h0[8], l0[8], h1[8], l1[8];
#pragma unroll
      for (int jj = 0; jj < 8; ++jj) {
        float2 cs2 = tb[jj];
        float o0 = fmaf(x0[jj], cs2.x, -x1[jj] * cs2.y);
        float o1 = fmaf(x1[jj], cs2.x, x0[jj] * cs2.y);
        unsigned short hbb = bf16rn(o0);
        h0[jj] = hbb;
        l0[jj] = bf16rn(o0 - __uint_as_float((unsigned)hbb << 16));
        hbb = bf16rn(o1);
        h1[jj] = hbb;
        l1[jj] = bf16rn(o1 - __uint_as_float((unsigned)hbb << 16));
      }
      char* base = (char*)qkbuf + (((size_t)((hb + jh) * 128 + t16)) << 12);
      uint4 v;
      v.x = (unsigned)h0[0] | ((unsigned)h0[1] << 16);
      v.y = (unsigned)h0[2] | ((unsigned)h0[3] << 16);
      v.z = (unsigned)h0[4] | ((unsigned)h0[5] << 16);
      v.w = (unsigned)h0[6] | ((unsigned)h0[7] << 16);
      ((uint4*)base)[lane] = v;
      v.x = (unsigned)h1[0] | ((unsigned)h1[1] << 16);
      v.y = (unsigned)h1[2] | ((unsigned)h1[3] << 16);
      v.z = (unsigned)h1[4] | ((unsigned)h1[5] << 16);
      v.w = (unsigned)h1[6] | ((unsigned)h1[7] << 16);
      ((uint4*)(base + 1024))[lane] = v;
      v.x = (unsigned)l0[0] | ((unsigned)l0[1] << 16);
      v.y = (unsigned)l0[2] | ((unsigned)l0[3] << 16);
      v.z = (unsigned)l0[4] | ((unsigned)l0[5] << 16);
      v.w = (unsigned)l0[6] | ((unsigned)l0[7] << 16);
      ((uint4*)(base + 2048))[lane] = v;
      v.x = (unsigned)l1[0] | ((unsigned)l1[1] << 16);
      v.y = (unsigned)l1[2] | ((unsigned)l1[3] << 16);
      v.z = (unsigned)l1[4] | ((unsigned)l1[5] << 16);
      v.w = (unsigned)l1[6] | ((unsigned)l1[7] << 16);
      ((uint4*)(base + 3072))[lane] = v;
    }
  } else {
    const int mbase = (blockIdx.y << 7) + (w << 4);
#pragma unroll
    for (int j = 0; j < 8; ++j) {
      const int ncol = (bxx << 7) + (j << 4);
      if (bxx < 24) {       // v: head-major f32
        const int h = (ncol & 1023) >> 6;
        float* base = Cv + (((size_t)h * T_DIM) << 6) + (ncol & 63) + col;
#pragma unroll
        for (int reg = 0; reg < 4; ++reg) {
          const int m = mbase + quad * 4 + reg;
          base[(size_t)m << 6] = acc[j][reg];
        }
      } else {              // gate: silu, row-major f32
        const int cb = (ncol & 1023) + col;
#pragma unroll
        for (int reg = 0; reg < 4; ++reg) {
          const int m = mbase + quad * 4 + reg;
          float vv = acc[j][reg];
          Cg[((size_t)m << 10) + cb] = vv / (1.f + expf(-vv));
        }
      }
    }
  }
}

// proj GEMM, 64x128 tiles, split-K x2: grid (8, 32, 2), 256 threads, 4/CU.
__global__ __launch_bounds__(256, 4) void mgemm_proj_kernel(
    const unsigned short* __restrict__ Ah, const unsigned short* __restrict__ Al,
    const unsigned short* __restrict__ Bh, const unsigned short* __restrict__ Bl,
    float* __restrict__ P0, float* __restrict__ P1)
{
  __shared__ __align__(16) unsigned short As[2 * 4 * 512];  // 8 KB
  __shared__ __align__(16) unsigned short Bs[2 * 8 * 512];  // 16 KB
  const int tid = threadIdx.x, lane = tid & 63, w = tid >> 6;
  const int mt0 = blockIdx.y << 2;
  const int nt0 = blockIdx.x << 3;
  const int kc0 = blockIdx.z << 4;
  float* Cout = blockIdx.z ? P1 : P0;

  f32x4 acc[8];
#pragma unroll
  for (int j = 0; j < 8; ++j) acc[j] = (f32x4){0.f, 0.f, 0.f, 0.f};

  for (int kc = kc0; kc < kc0 + 16; ++kc) {
#pragma unroll
    for (int li = 0; li < 6; ++li) {
      const int gi = w * 6 + li;
      const int isB = gi >= 8;
      const int t  = isB ? ((gi - 8) & 7) : (gi & 3);
      const int hl = isB ? ((gi - 8) >> 3) : (gi >> 2);
      const unsigned short* gbase = isB ? (hl ? Bl : Bh) : (hl ? Al : Ah);
      const int tg = (isB ? nt0 : mt0) + t;
      const unsigned short* g = gbase + (((size_t)(tg * 32 + kc) << 6) + lane) * 8;
      unsigned short* l = isB ? (Bs + hl * 4096 + t * 512) : (As + hl * 2048 + t * 512);
      gld_lds16(g, l);
    }
    __syncthreads();
    bf16x8 ah = *(const bf16x8*)&As[w * 512 + lane * 8];
    bf16x8 al = *(const bf16x8*)&As[2048 + w * 512 + lane * 8];
#pragma unroll
    for (int j = 0; j < 8; ++j) {
      bf16x8 bh = *(const bf16x8*)&Bs[j * 512 + lane * 8];
      bf16x8 bl = *(const bf16x8*)&Bs[4096 + j * 512 + lane * 8];
      acc[j] = __builtin_amdgcn_mfma_f32_16x16x32_bf16(ah, bh, acc[j], 0, 0, 0);
      acc[j] = __builtin_amdgcn_mfma_f32_16x16x32_bf16(ah, bl, acc[j], 0, 0, 0);
      acc[j] = __builtin_amdgcn_mfma_f32_16x16x32_bf16(al, bh, acc[j], 0, 0, 0);
    }
    __syncthreads();
  }

  const int col = lane & 15, quad = lane >> 4;
  const int mbase = (blockIdx.y << 6) + (w << 4);
  const int nbase = blockIdx.x << 7;
#pragma unroll
  for (int j = 0; j < 8; ++j)
#pragma unroll
    for (int reg = 0; reg < 4; ++reg) {
      const int m = mbase + quad * 4 + reg;
      Cout[((size_t)m << 10) + nbase + (j << 4) + col] = acc[j][reg];
    }
}

__global__ __launch_bounds__(256) void add2_kernel(
    const float* __restrict__ P0, const float* __restrict__ P1,
    float* __restrict__ out)
{
  const int i = (blockIdx.x * 256 + threadIdx.x) << 2;
  float4 a = *(const float4*)(P0 + i);
  float4 b = *(const float4*)(P1 + i);
  float4 o = {a.x + b.x, a.y + b.y, a.z + b.z, a.w + b.w};
  *(float4*)(out + i) = o;
}

// ---------------- attention: QTILE=8, 8 waves, ILP-pipelined ----------------
// Round-14 kernel + T5: s_setprio(1) around the score-phase MFMA cluster.
// Mechanism (guide m191): CU scheduler favors MFMA-entering waves over
// waves issuing loads; our attn has wave role diversity (2 independent
// blocks/CU, causal-LPT trip-count skew), unlike lockstep GEMM where T5 is
// null (m190) -- so applied to attn only. Zero register cost.
__global__ __launch_bounds__(512, 6) void attn_kernel(
    const float* __restrict__ qfrag, const float* __restrict__ kfrag,
    const float* __restrict__ v, const float* __restrict__ span_params,
    const float* __restrict__ gate,
    unsigned short* __restrict__ Yh, unsigned short* __restrict__ Yl)
{
  __shared__ __align__(16) char smem[QTILE * 1024 * 4];   // 32 KB
  float* sBase = (float*)smem;
  unsigned* histB = (unsigned*)smem;              // 8 KB (8 waves x 256)
  int* listJB = (int*)(smem + 8192);              // 4 KB
  unsigned* listUB = (unsigned*)(smem + 12288);   // 4 KB

  const int tid = threadIdx.x;
  const int lane = tid & 63;
  const int w = tid >> 6;                         // 0..7: wave owns row q0+w
  const int bx = gridDim.x - 1 - blockIdx.x;      // LPT: heavy blocks first
  const int q0 = bx << 3;
  const int h = blockIdx.y;
  const int qi = q0 + w;
  const int n = qi + 1;
  const float* vh = v + (((size_t)h * T_DIM) << 6);
  const int col = lane & 15, quad = lane >> 4;

  const int qt16 = bx >> 1;                       // 16-row frag tile index
  const int rlo = (bx & 1) << 3;                  // our 8 rows within the frag
  const uint4* qf = (const uint4*)((const char*)qfrag + (((size_t)(h * 128 + qt16)) << 12));
  bf16x8 Ah0 = ld_frag(qf + lane);
  bf16x8 Ah1 = ld_frag(qf + 64 + lane);
  bf16x8 Al0 = ld_frag(qf + 128 + lane);
  bf16x8 Al1 = ld_frag(qf + 192 + lane);

  unsigned uk[32];

#pragma unroll
  for (int ph = 0; ph < 2; ++ph) {
    const int tlo = ph << 6;
    const int thi = (qt16 < tlo + 63) ? qt16 : (tlo + 63);
    int tf = tlo + w;
    if (tf <= thi) {
      const uint4* kf = (const uint4*)((const char*)kfrag + (((size_t)(h * 128 + tf)) << 12));
      bf16x8 nBh0 = ld_frag(kf + lane);
      bf16x8 nBh1 = ld_frag(kf + 64 + lane);
      bf16x8 nBl0 = ld_frag(kf + 128 + lane);
      bf16x8 nBl1 = ld_frag(kf + 192 + lane);
      for (; tf <= thi; tf += 8) {
        const bf16x8 Bh0 = nBh0, Bh1 = nBh1, Bl0 = nBl0, Bl1 = nBl1;
        // prefetch next tile (re-load current as harmless dummy on last iter)
        const int tn = (tf + 8 <= thi) ? (tf + 8) : tf;
        const uint4* kfn = (const uint4*)((const char*)kfrag + (((size_t)(h * 128 + tn)) << 12));
        nBh0 = ld_frag(kfn + lane);
        nBh1 = ld_frag(kfn + 64 + lane);
        nBl0 = ld_frag(kfn + 128 + lane);
        nBl1 = ld_frag(kfn + 192 + lane);
        f32x4 acc = {0.f, 0.f, 0.f, 0.f};
        __builtin_amdgcn_s_setprio(1);
        acc = __builtin_amdgcn_mfma_f32_16x16x32_bf16(Ah0, Bh0, acc, 0, 0, 0);
        acc = __builtin_amdgcn_mfma_f32_16x16x32_bf16(Ah0, Bl0, acc, 0, 0, 0);
        acc = __builtin_amdgcn_mfma_f32_16x16x32_bf16(Al0, Bh0, acc, 0, 0, 0);
        acc = __builtin_amdgcn_mfma_f32_16x16x32_bf16(Ah1, Bh1, acc, 0, 0, 0);
        acc = __builtin_amdgcn_mfma_f32_16x16x32_bf16(Ah1, Bl1, acc, 0, 0, 0);
        acc = __builtin_amdgcn_mfma_f32_16x16x32_bf16(Al1, Bh1, acc, 0, 0, 0);
        __builtin_amdgcn_s_setprio(0);
        const int jcol = (tf << 4) + col;
#pragma unroll
        for (int r = 0; r < 4; ++r) {
          const int row8 = (quad << 2) + r - rlo;   // row within our 8
          if ((unsigned)row8 < 8u && jcol <= q0 + row8)
            sBase[row8 * 1024 + ((jcol & 1023) ^ (((row8 >> 2) & 1) << 4))] = acc[r];
        }
      }
    }
    __syncthreads();
#pragma unroll
    for (int cc = 0; cc < 2; ++cc) {
      const int c = (ph << 1) + cc;
      if ((c << 9) < n) {
#pragma unroll
        for (int i = 0; i < 8; ++i) {
          const int j = (((c << 3) + i) << 6) + lane;
          uk[(c << 3) + i] = (j < n)
              ? f2u(sBase[w * 1024 + ((j & 1023) ^ (((w >> 2) & 1) << 4))]) : PAD_KEY;
        }
      } else {
#pragma unroll
        for (int i = 0; i < 8; ++i) uk[(c << 3) + i] = PAD_KEY;
      }
    }
    __syncthreads();
  }

  unsigned* hist = histB + (w << 8);
  int* listJ = listJB + (w << 7);
  unsigned* listU = listUB + (w << 7);
  const float span = 2048.f * fminf(fmaxf(span_params[h], 0.f), 1.f);

  unsigned umax = 0;
#pragma unroll
  for (int i = 0; i < 32; ++i) umax = max(umax, uk[i]);
#pragma unroll
  for (int off = 32; off > 0; off >>= 1)
    umax = max(umax, (unsigned)__shfl_xor((int)umax, off, 64));
  const float mraw = u2f(umax);

  unsigned thresh_u = 0;
  if (n > TOPK_K) {
    unsigned want = TOPK_K;
    const unsigned bmax = umax >> 24;
    // ---- pass 1a: packed count of window bytes d=0..3 (regs + shfl) ----
    // one u64 accumulator, 4x16-bit fields; counts <= 2048 so no carries.
    unsigned long long c01 = 0;
#pragma unroll
    for (int c = 0; c < 4; ++c) {
      if ((c << 9) < n) {
#pragma unroll
        for (int i = 0; i < 8; ++i) {
          const unsigned u = uk[(c << 3) + i];
          const unsigned d = bmax - (u >> 24);
          if (u > PAD_KEY && d < 4u) c01 += 1ull << (d << 4);
        }
      }
    }
#pragma unroll
    for (int off = 32; off > 0; off >>= 1)
      c01 += __shfl_xor(c01, off, 64);
    unsigned cnt8[8];
    cnt8[0] = (unsigned)c01 & 0xFFFFu;
    cnt8[1] = ((unsigned)c01) >> 16;
    cnt8[2] = (unsigned)(c01 >> 32) & 0xFFFFu;
    cnt8[3] = (unsigned)(c01 >> 48);
    int m = -1;
    unsigned cumBefore = 0;
    bool exact = false;
    unsigned cum = 0;
#pragma unroll
    for (int b = 0; b < 4; ++b) {
      if (m < 0 && cum + cnt8[b] >= want) {
        m = b; cumBefore = cum; exact = (cum + cnt8[b] == want);
      }
      cum += cnt8[b];
    }
    if (m < 0) {
      // ---- rare pass 1b: window bytes d=4..7 (wave-uniform, fixed-trip) ----
      unsigned long long c23 = 0;
#pragma unroll
      for (int c = 0; c < 4; ++c) {
        if ((c << 9) < n) {
#pragma unroll
          for (int i = 0; i < 8; ++i) {
            const unsigned u = uk[(c << 3) + i];
            const unsigned d = bmax - (u >> 24) - 4u;
            if (u > PAD_KEY && d < 4u) c23 += 1ull << (d << 4);
          }
        }
      }
#pragma unroll
      for (int off = 32; off > 0; off >>= 1)
        c23 += __shfl_xor(c23, off, 64);
      cnt8[4] = (unsigned)c23 & 0xFFFFu;
      cnt8[5] = ((unsigned)c23) >> 16;
      cnt8[6] = (unsigned)(c23 >> 32) & 0xFFFFu;
      cnt8[7] = (unsigned)(c23 >> 48);
#pragma unroll
      for (int b = 4; b < 8; ++b) {
        if (m < 0 && cum + cnt8[b] >= want) {
          m = b; cumBefore = cum; exact = (cum + cnt8[b] == want);
        }
        cum += cnt8[b];
      }
    }
    unsigned prefix;
    int shift0;
    if (m >= 0) { prefix = (bmax - (unsigned)m) << 24; want -= cumBefore; shift0 = 16; }
    else        { prefix = 0; shift0 = 24; }   // window miss: full radix fallback
    if (m >= 0 && exact) {
      thresh_u = prefix;                        // exact boundary at byte granularity
    } else {
      for (int shift = shift0; shift >= 0; shift -= 8) {
        uint4 z4 = {0u, 0u, 0u, 0u};
        *(uint4*)&hist[lane << 2] = z4;
        __threadfence_block();
        const unsigned pm = (shift == 24) ? 0u : (0xFFFFFFFFu << (shift + 8));
#pragma unroll
        for (int c = 0; c < 4; ++c) {
          if ((c << 9) < n) {
#pragma unroll
            for (int i = 0; i < 8; ++i) {
              const unsigned u = uk[(c << 3) + i];
              if (u > PAD_KEY && (u & pm) == prefix)
                atomicAdd(&hist[(u >> shift) & 255u], 1u);
            }
          }
        }
        __threadfence_block();
        uint4 hv = *(const uint4*)&hist[lane << 2];
        unsigned loc = hv.x + hv.y + hv.z + hv.w;
        unsigned suf = loc;
#pragma unroll
        for (int off = 1; off < 64; off <<= 1) {
          unsigned t = __shfl_down(suf, off, 64);
          suf += (lane + off < 64) ? t : 0u;
        }
        unsigned sufE = suf - loc;
        unsigned S3 = sufE + hv.w;
        unsigned S2 = S3 + hv.z;
        unsigned S1 = S2 + hv.y;
        unsigned S0 = S1 + hv.x;
        const unsigned wt = want;
        int found = 0;
        unsigned pk = 0;
        if (S0 >= wt && S1 < wt)
          { found = 1; pk = ((unsigned)(4*lane+0) << 16) | ((S0 == wt) ? 0x8000u : 0u) | (wt - S1); }
        if (S1 >= wt && S2 < wt)
          { found = 1; pk = ((unsigned)(4*lane+1) << 16) | ((S1 == wt) ? 0x8000u : 0u) | (wt - S2); }
        if (S2 >= wt && S3 < wt)
          { found = 1; pk = ((unsigned)(4*lane+2) << 16) | ((S2 == wt) ? 0x8000u : 0u) | (wt - S3); }
        if (S3 >= wt && sufE < wt)
          { found = 1; pk = ((unsigned)(4*lane+3) << 16) | ((S3 == wt) ? 0x8000u : 0u) | (wt - sufE); }
        unsigned long long mk = __ballot(found);
        int src = __ffsll(mk) - 1;
        pk = __shfl(pk, src, 64);
        prefix |= (pk >> 16) << shift;
        want = pk & 0x7FFFu;
        if (pk & 0x8000u) break;
      }
      thresh_u = prefix;
    }
  }

  int cnt_run = 0;
#pragma unroll
  for (int c = 0; c < 4; ++c) {
    if ((c << 9) < n) {
#pragma unroll
      for (int i = 0; i < 8; ++i) {
        const int j = (((c << 3) + i) << 6) + lane;
        const unsigned u = uk[(c << 3) + i];
        const bool keep = (u >= thresh_u) && (u > PAD_KEY);
        unsigned long long mb = __ballot(keep);
        if (keep) {
          int pos = cnt_run + (int)__popcll(mb & ((1ull << lane) - 1ull));
          if (pos < LCAP) { listJ[pos] = j; listU[pos] = u; }
        }
        cnt_run += (int)__popcll(mb);
      }
    }
  }
  const int cnt = min(cnt_run, LCAP);
  __threadfence_block();

  float Zl = 0.f, Ul = 0.f;
  for (int e = lane; e < cnt; e += 64) {
    const unsigned u = listU[e];
    const int j = listJ[e];
    const float wv = __expf((u2f(u) - mraw) * 0.125f);
    const float dist = (float)(qi - j);
    const float msk = fminf(fmaxf((32.f + span - dist) * (1.f / 32.f), 0.f), 1.f);
    const float wm = wv * msk;
    Zl += wv;
    Ul += wm;
    listU[e] = __float_as_uint(wm);
  }
#pragma unroll
  for (int off = 32; off > 0; off >>= 1) {
    Zl += __shfl_xor(Zl, off, 64);
    Ul += __shfl_xor(Ul, off, 64);
  }
  const float scale = 1.f / (Ul + 1e-8f * Zl);
  __threadfence_block();

  // PV gather, unroll x4: 4 independent V-row loads in flight per iteration.
  const int g = lane >> 4;
  const int d4 = col << 2;
  float4 acc4 = {0.f, 0.f, 0.f, 0.f};
  for (int e0 = 0; e0 < cnt; e0 += 16) {
    int j0 = 0, j1 = 0, j2 = 0, j3 = 0;
    float wm0 = 0.f, wm1 = 0.f, wm2 = 0.f, wm3 = 0.f;
    {
      const int e = e0 + g;
      if (e < cnt) { j0 = listJ[e]; wm0 = __uint_as_float(listU[e]); }
    }
    {
      const int e = e0 + 4 + g;
      if (e < cnt) { j1 = listJ[e]; wm1 = __uint_as_float(listU[e]); }
    }
    {
      const int e = e0 + 8 + g;
      if (e < cnt) { j2 = listJ[e]; wm2 = __uint_as_float(listU[e]); }
    }
    {
      const int e = e0 + 12 + g;
      if (e < cnt) { j3 = listJ[e]; wm3 = __uint_as_float(listU[e]); }
    }
    const float4 v0 = *(const float4*)(vh + ((size_t)j0 << 6) + d4);
    const float4 v1 = *(const float4*)(vh + ((size_t)j1 << 6) + d4);
    const float4 v2 = *(const float4*)(vh + ((size_t)j2 << 6) + d4);
    const float4 v3 = *(const float4*)(vh + ((size_t)j3 << 6) + d4);
    acc4.x = fmaf(wm0, v0.x, acc4.x);
    acc4.y = fmaf(wm0, v0.y, acc4.y);
    acc4.z = fmaf(wm0, v0.z, acc4.z);
    acc4.w = fmaf(wm0, v0.w, acc4.w);
    acc4.x = fmaf(wm1, v1.x, acc4.x);
    acc4.y = fmaf(wm1, v1.y, acc4.y);
    acc4.z = fmaf(wm1, v1.z, acc4.z);
    acc4.w = fmaf(wm1, v1.w, acc4.w);
    acc4.x = fmaf(wm2, v2.x, acc4.x);
    acc4.y = fmaf(wm2, v2.y, acc4.y);
    acc4.z = fmaf(wm2, v2.z, acc4.z);
    acc4.w = fmaf(wm2, v2.w, acc4.w);
    acc4.x = fmaf(wm3, v3.x, acc4.x);
    acc4.y = fmaf(wm3, v3.y, acc4.y);
    acc4.z = fmaf(wm3, v3.z, acc4.z);
    acc4.w = fmaf(wm3, v3.w, acc4.w);
  }
#pragma unroll
  for (int off = 16; off <= 32; off <<= 1) {
    acc4.x += __shfl_xor(acc4.x, off, 64);
    acc4.y += __shfl_xor(acc4.y, off, 64);
    acc4.z += __shfl_xor(acc4.z, off, 64);
    acc4.w += __shfl_xor(acc4.w, off, 64);
  }
  if (g == 0) {
    // fused gate + frag-global hi/lo store (replaces gate_mul kernel).
    const int c0 = (h << 6) + d4;
    const float4 gv = *(const float4*)(gate + ((size_t)qi << 10) + c0);
    float p[4] = {acc4.x * scale * gv.x, acc4.y * scale * gv.y,
                  acc4.z * scale * gv.z, acc4.w * scale * gv.w};
    unsigned short ph[4], pl[4];
#pragma unroll
    for (int jj = 0; jj < 4; ++jj) {
      unsigned short hb = bf16rn(p[jj]);
      ph[jj] = hb;
      pl[jj] = bf16rn(p[jj] - __uint_as_float((unsigned)hb << 16));
    }
    const int k8 = c0 >> 3;
    const int t16 = qi >> 4, rr = qi & 15, kc = k8 >> 2, kq = k8 & 3;
    const size_t elem = (((size_t)(t16 * 32 + kc)) * 64 + ((kq << 4) | rr)) * 8 + (d4 & 7);
    ushort4 vh4 = {ph[0], ph[1], ph[2], ph[3]};
    ushort4 vl4 = {pl[0], pl[1], pl[2], pl[3]};
    *(ushort4*)(Yh + elem) = vh4;
    *(ushort4*)(Yl + elem) = vl4;
  }
}

extern "C" void kernel_launch(void* const* d_in, const int* in_sizes, int n_in,
                              void* d_out, int out_size, void* d_ws, size_t ws_size,
                              hipStream_t stream) {
  (void)in_sizes; (void)n_in; (void)out_size; (void)ws_size;
  const float* x           = (const float*)d_in[0];
  const float* w_attn      = (const float*)d_in[1];
  const float* w_proj      = (const float*)d_in[2];
  const float* w_gate      = (const float*)d_in[3];
  const float* span_params = (const float*)d_in[4];
  float* out = (float*)d_out;

  char* ws = (char*)d_ws;
  const size_t MB = 1024 * 1024;
  float* q     = (float*)(ws);            // 8 MB (qfrag direct; P0 after attn)
  float* k     = (float*)(ws + 8 * MB);   // 8 MB (kfrag direct; P1 after attn)
  float* v     = (float*)(ws + 16 * MB);  // 8 MB
  float* gate  = (float*)(ws + 24 * MB);  // 8 MB
  unsigned short* xf_h  = (unsigned short*)(ws + 40 * MB);  // 4 MB
  unsigned short* xf_l  = (unsigned short*)(ws + 44 * MB);  // 4 MB
  unsigned short* wqg_h = (unsigned short*)(ws + 48 * MB);  // 8 MB
  unsigned short* wqg_l = (unsigned short*)(ws + 56 * MB);  // 8 MB
  unsigned short* wfp_h = (unsigned short*)(ws + 64 * MB);  // 2 MB
  unsigned short* wfp_l = (unsigned short*)(ws + 66 * MB);  // 2 MB
  unsigned short* ygf_h = (unsigned short*)(ws + 68 * MB);  // 4 MB
  unsigned short* ygf_l = (unsigned short*)(ws + 72 * MB);  // 4 MB
  float2* rope_tab = (float2*)(ws + 76 * MB);               // 0.5 MB
  float* P0 = q;   // dead after attn
  float* P1 = k;

  convert_all_kernel<<<3840, 256, 0, stream>>>(
      x, w_attn, w_gate, w_proj, xf_h, xf_l, wqg_h, wqg_l, wfp_h, wfp_l, rope_tab);
  mgemm_qkvg_kernel<<<dim3(32, 16), 512, 0, stream>>>(
      xf_h, xf_l, wqg_h, wqg_l, q, k, v, gate, rope_tab);
  attn_kernel<<<dim3(T_DIM / QTILE, H_DIM), 512, 0, stream>>>(
      q, k, v, span_params, gate, ygf_h, ygf_l);
  mgemm_proj_kernel<<<dim3(8, 32, 2), 256, 0, stream>>>(
      ygf_h, ygf_l, wfp_h, wfp_l, P0, P1);
  add2_kernel<<<(T_DIM * C_DIM) / 1024, 256, 0, stream>>>(P0, P1, out);
}

// Round 16
// 275.412 us; speedup vs baseline: 1.1367x; 1.1367x over previous
//
#include <hip/hip_runtime.h>
#include <math.h>

#define T_DIM 2048
#define C_DIM 1024
#define H_DIM 16
#define HD 64
#define TOPK_K 64
#define QTILE 8
#define LCAP 128

typedef __attribute__((ext_vector_type(8))) __bf16 bf16x8;
typedef __attribute__((ext_vector_type(4))) float f32x4;

__device__ __forceinline__ unsigned short bf16rn(float x) {
  unsigned u = __float_as_uint(x);
  return (unsigned short)((u + 0x7FFFu + ((u >> 16) & 1u)) >> 16);
}
__device__ __forceinline__ unsigned f2u(float f) {
  unsigned u = __float_as_uint(f);
  return (u & 0x80000000u) ? ~u : (u | 0x80000000u);
}
__device__ __forceinline__ float u2f(unsigned u) {
  unsigned v = (u & 0x80000000u) ? (u & 0x7FFFFFFFu) : ~u;
  return __uint_as_float(v);
}
__device__ __forceinline__ bf16x8 ld_frag(const uint4* p) {
  uint4 u = *p;
  return __builtin_bit_cast(bf16x8, u);
}
#define PAD_KEY 0x007FFFFFu   // f2u(-INF); real raw scores always exceed this

// ------- fused fp32 -> frag-global bf16 hi/lo converter + rope table --------
__global__ __launch_bounds__(256) void convert_all_kernel(
    const float* __restrict__ x, const float* __restrict__ wa,
    const float* __restrict__ wg, const float* __restrict__ wp,
    unsigned short* __restrict__ xh, unsigned short* __restrict__ xl,
    unsigned short* __restrict__ wqgh, unsigned short* __restrict__ wqgl,
    unsigned short* __restrict__ wph, unsigned short* __restrict__ wpl,
    float2* __restrict__ tab)
{
  const int tid = blockIdx.x * 256 + threadIdx.x;
  const int k8 = tid & 127, r = tid >> 7;
  if (r >= 7168) {   // rope sincos table tail: 512 r-slots x 128 = 65536
    const int e = ((r - 7168) << 7) | k8;
    const int t = e >> 5, d = e & 31;
    double invf = exp(-(double)d * (log(10000.0) / 32.0));
    double ang = (double)t * invf;
    tab[e] = make_float2((float)cos(ang), (float)sin(ang));
    return;
  }
  const float* src;
  unsigned short *Dh, *Dl;
  int srow, drow;
  if (r < 2048)      { src = x;  Dh = xh;   Dl = xl;   srow = r;        drow = r; }
  else if (r < 5120) { src = wa; Dh = wqgh; Dl = wqgl; srow = r - 2048; drow = r - 2048; }
  else if (r < 6144) { src = wg; Dh = wqgh; Dl = wqgl; srow = r - 5120; drow = r - 2048; }
  else               { src = wp; Dh = wph;  Dl = wpl;  srow = r - 6144; drow = r - 6144; }
  const float* s = src + ((size_t)srow << 10) + (k8 << 3);
  float4 a = *(const float4*)s;
  float4 b = *(const float4*)(s + 4);
  float xs[8] = {a.x, a.y, a.z, a.w, b.x, b.y, b.z, b.w};
  unsigned hi[8], lo[8];
#pragma unroll
  for (int jj = 0; jj < 8; ++jj) {
    unsigned short hb = bf16rn(xs[jj]);
    hi[jj] = hb;
    lo[jj] = bf16rn(xs[jj] - __uint_as_float((unsigned)hb << 16));
  }
  const int t16 = drow >> 4, rr = drow & 15, kc = k8 >> 2, kq = k8 & 3;
  const size_t elem = (((size_t)(t16 * 32 + kc)) * 64 + ((kq << 4) | rr)) * 8;
  uint4 vh, vl;
  vh.x = hi[0] | (hi[1] << 16); vh.y = hi[2] | (hi[3] << 16);
  vh.z = hi[4] | (hi[5] << 16); vh.w = hi[6] | (hi[7] << 16);
  vl.x = lo[0] | (lo[1] << 16); vl.y = lo[2] | (lo[3] << 16);
  vl.z = lo[4] | (lo[5] << 16); vl.w = lo[6] | (lo[7] << 16);
  *(uint4*)(Dh + elem) = vh;
  *(uint4*)(Dl + elem) = vl;
}

// ---------------- split-bf16 MFMA GEMM machinery ----------------
__device__ __forceinline__ void gld_lds16(const unsigned short* g, unsigned short* l) {
  __builtin_amdgcn_global_load_lds(
      (const __attribute__((address_space(1))) unsigned int*)g,
      (__attribute__((address_space(3))) unsigned int*)l, 16, 0, 0);
}

// qkv+gate GEMM, 128x128 tiles: grid (32, 16), 512 threads (8 waves), 2/CU.
// q/k blocks (bx<16) fuse the RoPE + attention-frag hi/lo split into the
// epilogue (deletes prep_frag + 32 MB of q/k f32 round-trip).
__global__ __launch_bounds__(512, 4) void mgemm_qkvg_kernel(
    const unsigned short* __restrict__ Ah, const unsigned short* __restrict__ Al,
    const unsigned short* __restrict__ Bh, const unsigned short* __restrict__ Bl,
    float* __restrict__ Cq, float* __restrict__ Ck, float* __restrict__ Cv,
    float* __restrict__ Cg, const float2* __restrict__ tab)
{
  __shared__ __align__(16) char smemAll[34816];  // As 16K | Bs 16K; rope 33.8K overlay
  unsigned short* As = (unsigned short*)smemAll;
  unsigned short* Bs = (unsigned short*)(smemAll + 16384);
  const int tid = threadIdx.x, lane = tid & 63, w = tid >> 6;
  const int mt0 = blockIdx.y << 3;   // 8 tiles16 of A rows
  const int nt0 = blockIdx.x << 3;   // 8 tiles16 of B rows

  f32x4 acc[8];
#pragma unroll
  for (int j = 0; j < 8; ++j) acc[j] = (f32x4){0.f, 0.f, 0.f, 0.f};

  for (int kc = 0; kc < 32; ++kc) {
#pragma unroll
    for (int li = 0; li < 4; ++li) {
      const int gi = (w << 2) + li;        // 0..31
      const int isB = gi >= 16;
      const int gb = gi & 15;
      const int t  = gb & 7;
      const int hl = gb >> 3;
      const unsigned short* gbase = isB ? (hl ? Bl : Bh) : (hl ? Al : Ah);
      const int tg = (isB ? nt0 : mt0) + t;
      const unsigned short* g = gbase + (((size_t)(tg * 32 + kc) << 6) + lane) * 8;
      unsigned short* l = (isB ? Bs : As) + hl * 4096 + t * 512;
      gld_lds16(g, l);
    }
    __syncthreads();
    bf16x8 ah = *(const bf16x8*)&As[w * 512 + lane * 8];
    bf16x8 al = *(const bf16x8*)&As[4096 + w * 512 + lane * 8];
#pragma unroll
    for (int j = 0; j < 8; ++j) {
      bf16x8 bh = *(const bf16x8*)&Bs[j * 512 + lane * 8];
      bf16x8 bl = *(const bf16x8*)&Bs[4096 + j * 512 + lane * 8];
      acc[j] = __builtin_amdgcn_mfma_f32_16x16x32_bf16(ah, bh, acc[j], 0, 0, 0);
      acc[j] = __builtin_amdgcn_mfma_f32_16x16x32_bf16(ah, bl, acc[j], 0, 0, 0);
      acc[j] = __builtin_amdgcn_mfma_f32_16x16x32_bf16(al, bh, acc[j], 0, 0, 0);
    }
    __syncthreads();
  }

  const int col = lane & 15, quad = lane >> 4;
  const int bxx = blockIdx.x;
  if (bxx < 16) {
    // ---- fused RoPE + frag-split for q (bxx<8) / k (bxx>=8) ----
    float* W = (float*)smemAll + w * (16 * 66);   // wave-private; As/Bs dead
    float* qkbuf = (bxx < 8) ? Cq : Ck;
    const int hb = (bxx & 7) << 1;                // head pair base
    const int t16 = (blockIdx.y << 3) + w;        // this wave's frag tile16
    const int t = (t16 << 4) + col;               // row on the read side (nr=col)
    const float2* tb = tab + t * 32 + (quad << 3);
#pragma unroll
    for (int jh = 0; jh < 2; ++jh) {
      // scatter this head's raw acc into the wave's LDS tile [row][d]
#pragma unroll
      for (int j2 = 0; j2 < 4; ++j2)
#pragma unroll
        for (int reg = 0; reg < 4; ++reg)
          W[(quad * 4 + reg) * 66 + (j2 << 4) + col] = acc[(jh << 2) + j2][reg];
      // read back in frag order (lane -> row=col, d0=quad*8) and run
      // prep_frag's exact RoPE + hi/lo split
      const float* rowp = W + col * 66;
      float x0[8], x1[8];
#pragma unroll
      for (int jj = 0; jj < 8; ++jj) {
        x0[jj] = rowp[(quad << 3) + jj];
        x1[jj] = rowp[32 + (quad << 3) + jj];
      }
      unsigned short h0[8], l0[8], h1[8], l1[8];
#pragma unroll
      for (int jj = 0; jj < 8; ++jj) {
        float2 cs2 = tb[jj];
        float o0 = fmaf(x0[jj], cs2.x, -x1[jj] * cs2.y);
        float o1 = fmaf(x1[jj], cs2.x, x0[jj] * cs2.y);
        unsigned short hbb = bf16rn(o0);
        h0[jj] = hbb;
        l0[jj] = bf16rn(o0 - __uint_as_float((unsigned)hbb << 16));
        hbb = bf16rn(o1);
        h1[jj] = hbb;
        l1[jj] = bf16rn(o1 - __uint_as_float((unsigned)hbb << 16));
      }
      char* base = (char*)qkbuf + (((size_t)((hb + jh) * 128 + t16)) << 12);
      uint4 v;
      v.x = (unsigned)h0[0] | ((unsigned)h0[1] << 16);
      v.y = (unsigned)h0[2] | ((unsigned)h0[3] << 16);
      v.z = (unsigned)h0[4] | ((unsigned)h0[5] << 16);
      v.w = (unsigned)h0[6] | ((unsigned)h0[7] << 16);
      ((uint4*)base)[lane] = v;
      v.x = (unsigned)h1[0] | ((unsigned)h1[1] << 16);
      v.y = (unsigned)h1[2] | ((unsigned)h1[3] << 16);
      v.z = (unsigned)h1[4] | ((unsigned)h1[5] << 16);
      v.w = (unsigned)h1[6] | ((unsigned)h1[7] << 16);
      ((uint4*)(base + 1024))[lane] = v;
      v.x = (unsigned)l0[0] | ((unsigned)l0[1] << 16);
      v.y = (unsigned)l0[2] | ((unsigned)l0[3] << 16);
      v.z = (unsigned)l0[4] | ((unsigned)l0[5] << 16);
      v.w = (unsigned)l0[6] | ((unsigned)l0[7] << 16);
      ((uint4*)(base + 2048))[lane] = v;
      v.x = (unsigned)l1[0] | ((unsigned)l1[1] << 16);
      v.y = (unsigned)l1[2] | ((unsigned)l1[3] << 16);
      v.z = (unsigned)l1[4] | ((unsigned)l1[5] << 16);
      v.w = (unsigned)l1[6] | ((unsigned)l1[7] << 16);
      ((uint4*)(base + 3072))[lane] = v;
    }
  } else {
    const int mbase = (blockIdx.y << 7) + (w << 4);
#pragma unroll
    for (int j = 0; j < 8; ++j) {
      const int ncol = (bxx << 7) + (j << 4);
      if (bxx < 24) {       // v: head-major f32
        const int h = (ncol & 1023) >> 6;
        float* base = Cv + (((size_t)h * T_DIM) << 6) + (ncol & 63) + col;
#pragma unroll
        for (int reg = 0; reg < 4; ++reg) {
          const int m = mbase + quad * 4 + reg;
          base[(size_t)m << 6] = acc[j][reg];
        }
      } else {              // gate: silu, row-major f32
        const int cb = (ncol & 1023) + col;
#pragma unroll
        for (int reg = 0; reg < 4; ++reg) {
          const int m = mbase + quad * 4 + reg;
          float vv = acc[j][reg];
          Cg[((size_t)m << 10) + cb] = vv / (1.f + expf(-vv));
        }
      }
    }
  }
}

// proj GEMM, 64x128 tiles, split-K x2: grid (8, 32, 2), 256 threads, 4/CU.
__global__ __launch_bounds__(256, 4) void mgemm_proj_kernel(
    const unsigned short* __restrict__ Ah, const unsigned short* __restrict__ Al,
    const unsigned short* __restrict__ Bh, const unsigned short* __restrict__ Bl,
    float* __restrict__ P0, float* __restrict__ P1)
{
  __shared__ __align__(16) unsigned short As[2 * 4 * 512];  // 8 KB
  __shared__ __align__(16) unsigned short Bs[2 * 8 * 512];  // 16 KB
  const int tid = threadIdx.x, lane = tid & 63, w = tid >> 6;
  const int mt0 = blockIdx.y << 2;
  const int nt0 = blockIdx.x << 3;
  const int kc0 = blockIdx.z << 4;
  float* Cout = blockIdx.z ? P1 : P0;

  f32x4 acc[8];
#pragma unroll
  for (int j = 0; j < 8; ++j) acc[j] = (f32x4){0.f, 0.f, 0.f, 0.f};

  for (int kc = kc0; kc < kc0 + 16; ++kc) {
#pragma unroll
    for (int li = 0; li < 6; ++li) {
      const int gi = w * 6 + li;
      const int isB = gi >= 8;
      const int t  = isB ? ((gi - 8) & 7) : (gi & 3);
      const int hl = isB ? ((gi - 8) >> 3) : (gi >> 2);
      const unsigned short* gbase = isB ? (hl ? Bl : Bh) : (hl ? Al : Ah);
      const int tg = (isB ? nt0 : mt0) + t;
      const unsigned short* g = gbase + (((size_t)(tg * 32 + kc) << 6) + lane) * 8;
      unsigned short* l = isB ? (Bs + hl * 4096 + t * 512) : (As + hl * 2048 + t * 512);
      gld_lds16(g, l);
    }
    __syncthreads();
    bf16x8 ah = *(const bf16x8*)&As[w * 512 + lane * 8];
    bf16x8 al = *(const bf16x8*)&As[2048 + w * 512 + lane * 8];
#pragma unroll
    for (int j = 0; j < 8; ++j) {
      bf16x8 bh = *(const bf16x8*)&Bs[j * 512 + lane * 8];
      bf16x8 bl = *(const bf16x8*)&Bs[4096 + j * 512 + lane * 8];
      acc[j] = __builtin_amdgcn_mfma_f32_16x16x32_bf16(ah, bh, acc[j], 0, 0, 0);
      acc[j] = __builtin_amdgcn_mfma_f32_16x16x32_bf16(ah, bl, acc[j], 0, 0, 0);
      acc[j] = __builtin_amdgcn_mfma_f32_16x16x32_bf16(al, bh, acc[j], 0, 0, 0);
    }
    __syncthreads();
  }

  const int col = lane & 15, quad = lane >> 4;
  const int mbase = (blockIdx.y << 6) + (w << 4);
  const int nbase = blockIdx.x << 7;
#pragma unroll
  for (int j = 0; j < 8; ++j)
#pragma unroll
    for (int reg = 0; reg < 4; ++reg) {
      const int m = mbase + quad * 4 + reg;
      Cout[((size_t)m << 10) + nbase + (j << 4) + col] = acc[j][reg];
    }
}

__global__ __launch_bounds__(256) void add2_kernel(
    const float* __restrict__ P0, const float* __restrict__ P1,
    float* __restrict__ out)
{
  const int i = (blockIdx.x * 256 + threadIdx.x) << 2;
  float4 a = *(const float4*)(P0 + i);
  float4 b = *(const float4*)(P1 + i);
  float4 o = {a.x + b.x, a.y + b.y, a.z + b.z, a.w + b.w};
  *(float4*)(out + i) = o;
}

// ---------------- attention: QTILE=8, 8 waves, ILP-pipelined ----------------
// Round-14 kernel (best measured: attn 132 us, no spill). T5 setprio was
// tried in round 15 and REGRESSED (spill: WRITE 8.2->147 MB) -- the setprio
// fences lengthen live ranges past the 84-reg cap. Do not re-add.
__global__ __launch_bounds__(512, 6) void attn_kernel(
    const float* __restrict__ qfrag, const float* __restrict__ kfrag,
    const float* __restrict__ v, const float* __restrict__ span_params,
    const float* __restrict__ gate,
    unsigned short* __restrict__ Yh, unsigned short* __restrict__ Yl)
{
  __shared__ __align__(16) char smem[QTILE * 1024 * 4];   // 32 KB
  float* sBase = (float*)smem;
  unsigned* histB = (unsigned*)smem;              // 8 KB (8 waves x 256)
  int* listJB = (int*)(smem + 8192);              // 4 KB
  unsigned* listUB = (unsigned*)(smem + 12288);   // 4 KB

  const int tid = threadIdx.x;
  const int lane = tid & 63;
  const int w = tid >> 6;                         // 0..7: wave owns row q0+w
  const int bx = gridDim.x - 1 - blockIdx.x;      // LPT: heavy blocks first
  const int q0 = bx << 3;
  const int h = blockIdx.y;
  const int qi = q0 + w;
  const int n = qi + 1;
  const float* vh = v + (((size_t)h * T_DIM) << 6);
  const int col = lane & 15, quad = lane >> 4;

  const int qt16 = bx >> 1;                       // 16-row frag tile index
  const int rlo = (bx & 1) << 3;                  // our 8 rows within the frag
  const uint4* qf = (const uint4*)((const char*)qfrag + (((size_t)(h * 128 + qt16)) << 12));
  bf16x8 Ah0 = ld_frag(qf + lane);
  bf16x8 Ah1 = ld_frag(qf + 64 + lane);
  bf16x8 Al0 = ld_frag(qf + 128 + lane);
  bf16x8 Al1 = ld_frag(qf + 192 + lane);

  unsigned uk[32];

#pragma unroll
  for (int ph = 0; ph < 2; ++ph) {
    const int tlo = ph << 6;
    const int thi = (qt16 < tlo + 63) ? qt16 : (tlo + 63);
    int tf = tlo + w;
    if (tf <= thi) {
      const uint4* kf = (const uint4*)((const char*)kfrag + (((size_t)(h * 128 + tf)) << 12));
      bf16x8 nBh0 = ld_frag(kf + lane);
      bf16x8 nBh1 = ld_frag(kf + 64 + lane);
      bf16x8 nBl0 = ld_frag(kf + 128 + lane);
      bf16x8 nBl1 = ld_frag(kf + 192 + lane);
      for (; tf <= thi; tf += 8) {
        const bf16x8 Bh0 = nBh0, Bh1 = nBh1, Bl0 = nBl0, Bl1 = nBl1;
        // prefetch next tile (re-load current as harmless dummy on last iter)
        const int tn = (tf + 8 <= thi) ? (tf + 8) : tf;
        const uint4* kfn = (const uint4*)((const char*)kfrag + (((size_t)(h * 128 + tn)) << 12));
        nBh0 = ld_frag(kfn + lane);
        nBh1 = ld_frag(kfn + 64 + lane);
        nBl0 = ld_frag(kfn + 128 + lane);
        nBl1 = ld_frag(kfn + 192 + lane);
        f32x4 acc = {0.f, 0.f, 0.f, 0.f};
        acc = __builtin_amdgcn_mfma_f32_16x16x32_bf16(Ah0, Bh0, acc, 0, 0, 0);
        acc = __builtin_amdgcn_mfma_f32_16x16x32_bf16(Ah0, Bl0, acc, 0, 0, 0);
        acc = __builtin_amdgcn_mfma_f32_16x16x32_bf16(Al0, Bh0, acc, 0, 0, 0);
        acc = __builtin_amdgcn_mfma_f32_16x16x32_bf16(Ah1, Bh1, acc, 0, 0, 0);
        acc = __builtin_amdgcn_mfma_f32_16x16x32_bf16(Ah1, Bl1, acc, 0, 0, 0);
        acc = __builtin_amdgcn_mfma_f32_16x16x32_bf16(Al1, Bh1, acc, 0, 0, 0);
        const int jcol = (tf << 4) + col;
#pragma unroll
        for (int r = 0; r < 4; ++r) {
          const int row8 = (quad << 2) + r - rlo;   // row within our 8
          if ((unsigned)row8 < 8u && jcol <= q0 + row8)
            sBase[row8 * 1024 + ((jcol & 1023) ^ (((row8 >> 2) & 1) << 4))] = acc[r];
        }
      }
    }
    __syncthreads();
#pragma unroll
    for (int cc = 0; cc < 2; ++cc) {
      const int c = (ph << 1) + cc;
      if ((c << 9) < n) {
#pragma unroll
        for (int i = 0; i < 8; ++i) {
          const int j = (((c << 3) + i) << 6) + lane;
          uk[(c << 3) + i] = (j < n)
              ? f2u(sBase[w * 1024 + ((j & 1023) ^ (((w >> 2) & 1) << 4))]) : PAD_KEY;
        }
      } else {
#pragma unroll
        for (int i = 0; i < 8; ++i) uk[(c << 3) + i] = PAD_KEY;
      }
    }
    __syncthreads();
  }

  unsigned* hist = histB + (w << 8);
  int* listJ = listJB + (w << 7);
  unsigned* listU = listUB + (w << 7);
  const float span = 2048.f * fminf(fmaxf(span_params[h], 0.f), 1.f);

  unsigned umax = 0;
#pragma unroll
  for (int i = 0; i < 32; ++i) umax = max(umax, uk[i]);
#pragma unroll
  for (int off = 32; off > 0; off >>= 1)
    umax = max(umax, (unsigned)__shfl_xor((int)umax, off, 64));
  const float mraw = u2f(umax);

  unsigned thresh_u = 0;
  if (n > TOPK_K) {
    unsigned want = TOPK_K;
    const unsigned bmax = umax >> 24;
    // ---- pass 1a: packed count of window bytes d=0..3 (regs + shfl) ----
    // one u64 accumulator, 4x16-bit fields; counts <= 2048 so no carries.
    unsigned long long c01 = 0;
#pragma unroll
    for (int c = 0; c < 4; ++c) {
      if ((c << 9) < n) {
#pragma unroll
        for (int i = 0; i < 8; ++i) {
          const unsigned u = uk[(c << 3) + i];
          const unsigned d = bmax - (u >> 24);
          if (u > PAD_KEY && d < 4u) c01 += 1ull << (d << 4);
        }
      }
    }
#pragma unroll
    for (int off = 32; off > 0; off >>= 1)
      c01 += __shfl_xor(c01, off, 64);
    unsigned cnt8[8];
    cnt8[0] = (unsigned)c01 & 0xFFFFu;
    cnt8[1] = ((unsigned)c01) >> 16;
    cnt8[2] = (unsigned)(c01 >> 32) & 0xFFFFu;
    cnt8[3] = (unsigned)(c01 >> 48);
    int m = -1;
    unsigned cumBefore = 0;
    bool exact = false;
    unsigned cum = 0;
#pragma unroll
    for (int b = 0; b < 4; ++b) {
      if (m < 0 && cum + cnt8[b] >= want) {
        m = b; cumBefore = cum; exact = (cum + cnt8[b] == want);
      }
      cum += cnt8[b];
    }
    if (m < 0) {
      // ---- rare pass 1b: window bytes d=4..7 (wave-uniform, fixed-trip) ----
      unsigned long long c23 = 0;
#pragma unroll
      for (int c = 0; c < 4; ++c) {
        if ((c << 9) < n) {
#pragma unroll
          for (int i = 0; i < 8; ++i) {
            const unsigned u = uk[(c << 3) + i];
            const unsigned d = bmax - (u >> 24) - 4u;
            if (u > PAD_KEY && d < 4u) c23 += 1ull << (d << 4);
          }
        }
      }
#pragma unroll
      for (int off = 32; off > 0; off >>= 1)
        c23 += __shfl_xor(c23, off, 64);
      cnt8[4] = (unsigned)c23 & 0xFFFFu;
      cnt8[5] = ((unsigned)c23) >> 16;
      cnt8[6] = (unsigned)(c23 >> 32) & 0xFFFFu;
      cnt8[7] = (unsigned)(c23 >> 48);
#pragma unroll
      for (int b = 4; b < 8; ++b) {
        if (m < 0 && cum + cnt8[b] >= want) {
          m = b; cumBefore = cum; exact = (cum + cnt8[b] == want);
        }
        cum += cnt8[b];
      }
    }
    unsigned prefix;
    int shift0;
    if (m >= 0) { prefix = (bmax - (unsigned)m) << 24; want -= cumBefore; shift0 = 16; }
    else        { prefix = 0; shift0 = 24; }   // window miss: full radix fallback
    if (m >= 0 && exact) {
      thresh_u = prefix;                        // exact boundary at byte granularity
    } else {
      for (int shift = shift0; shift >= 0; shift -= 8) {
        uint4 z4 = {0u, 0u, 0u, 0u};
        *(uint4*)&hist[lane << 2] = z4;
        __threadfence_block();
        const unsigned pm = (shift == 24) ? 0u : (0xFFFFFFFFu << (shift + 8));
#pragma unroll
        for (int c = 0; c < 4; ++c) {
          if ((c << 9) < n) {
#pragma unroll
            for (int i = 0; i < 8; ++i) {
              const unsigned u = uk[(c << 3) + i];
              if (u > PAD_KEY && (u & pm) == prefix)
                atomicAdd(&hist[(u >> shift) & 255u], 1u);
            }
          }
        }
        __threadfence_block();
        uint4 hv = *(const uint4*)&hist[lane << 2];
        unsigned loc = hv.x + hv.y + hv.z + hv.w;
        unsigned suf = loc;
#pragma unroll
        for (int off = 1; off < 64; off <<= 1) {
          unsigned t = __shfl_down(suf, off, 64);
          suf += (lane + off < 64) ? t : 0u;
        }
        unsigned sufE = suf - loc;
        unsigned S3 = sufE + hv.w;
        unsigned S2 = S3 + hv.z;
        unsigned S1 = S2 + hv.y;
        unsigned S0 = S1 + hv.x;
        const unsigned wt = want;
        int found = 0;
        unsigned pk = 0;
        if (S0 >= wt && S1 < wt)
          { found = 1; pk = ((unsigned)(4*lane+0) << 16) | ((S0 == wt) ? 0x8000u : 0u) | (wt - S1); }
        if (S1 >= wt && S2 < wt)
          { found = 1; pk = ((unsigned)(4*lane+1) << 16) | ((S1 == wt) ? 0x8000u : 0u) | (wt - S2); }
        if (S2 >= wt && S3 < wt)
          { found = 1; pk = ((unsigned)(4*lane+2) << 16) | ((S2 == wt) ? 0x8000u : 0u) | (wt - S3); }
        if (S3 >= wt && sufE < wt)
          { found = 1; pk = ((unsigned)(4*lane+3) << 16) | ((S3 == wt) ? 0x8000u : 0u) | (wt - sufE); }
        unsigned long long mk = __ballot(found);
        int src = __ffsll(mk) - 1;
        pk = __shfl(pk, src, 64);
        prefix |= (pk >> 16) << shift;
        want = pk & 0x7FFFu;
        if (pk & 0x8000u) break;
      }
      thresh_u = prefix;
    }
  }

  int cnt_run = 0;
#pragma unroll
  for (int c = 0; c < 4; ++c) {
    if ((c << 9) < n) {
#pragma unroll
      for (int i = 0; i < 8; ++i) {
        const int j = (((c << 3) + i) << 6) + lane;
        const unsigned u = uk[(c << 3) + i];
        const bool keep = (u >= thresh_u) && (u > PAD_KEY);
        unsigned long long mb = __ballot(keep);
        if (keep) {
          int pos = cnt_run + (int)__popcll(mb & ((1ull << lane) - 1ull));
          if (pos < LCAP) { listJ[pos] = j; listU[pos] = u; }
        }
        cnt_run += (int)__popcll(mb);
      }
    }
  }
  const int cnt = min(cnt_run, LCAP);
  __threadfence_block();

  float Zl = 0.f, Ul = 0.f;
  for (int e = lane; e < cnt; e += 64) {
    const unsigned u = listU[e];
    const int j = listJ[e];
    const float wv = __expf((u2f(u) - mraw) * 0.125f);
    const float dist = (float)(qi - j);
    const float msk = fminf(fmaxf((32.f + span - dist) * (1.f / 32.f), 0.f), 1.f);
    const float wm = wv * msk;
    Zl += wv;
    Ul += wm;
    listU[e] = __float_as_uint(wm);
  }
#pragma unroll
  for (int off = 32; off > 0; off >>= 1) {
    Zl += __shfl_xor(Zl, off, 64);
    Ul += __shfl_xor(Ul, off, 64);
  }
  const float scale = 1.f / (Ul + 1e-8f * Zl);
  __threadfence_block();

  // PV gather, unroll x4: 4 independent V-row loads in flight per iteration.
  const int g = lane >> 4;
  const int d4 = col << 2;
  float4 acc4 = {0.f, 0.f, 0.f, 0.f};
  for (int e0 = 0; e0 < cnt; e0 += 16) {
    int j0 = 0, j1 = 0, j2 = 0, j3 = 0;
    float wm0 = 0.f, wm1 = 0.f, wm2 = 0.f, wm3 = 0.f;
    {
      const int e = e0 + g;
      if (e < cnt) { j0 = listJ[e]; wm0 = __uint_as_float(listU[e]); }
    }
    {
      const int e = e0 + 4 + g;
      if (e < cnt) { j1 = listJ[e]; wm1 = __uint_as_float(listU[e]); }
    }
    {
      const int e = e0 + 8 + g;
      if (e < cnt) { j2 = listJ[e]; wm2 = __uint_as_float(listU[e]); }
    }
    {
      const int e = e0 + 12 + g;
      if (e < cnt) { j3 = listJ[e]; wm3 = __uint_as_float(listU[e]); }
    }
    const float4 v0 = *(const float4*)(vh + ((size_t)j0 << 6) + d4);
    const float4 v1 = *(const float4*)(vh + ((size_t)j1 << 6) + d4);
    const float4 v2 = *(const float4*)(vh + ((size_t)j2 << 6) + d4);
    const float4 v3 = *(const float4*)(vh + ((size_t)j3 << 6) + d4);
    acc4.x = fmaf(wm0, v0.x, acc4.x);
    acc4.y = fmaf(wm0, v0.y, acc4.y);
    acc4.z = fmaf(wm0, v0.z, acc4.z);
    acc4.w = fmaf(wm0, v0.w, acc4.w);
    acc4.x = fmaf(wm1, v1.x, acc4.x);
    acc4.y = fmaf(wm1, v1.y, acc4.y);
    acc4.z = fmaf(wm1, v1.z, acc4.z);
    acc4.w = fmaf(wm1, v1.w, acc4.w);
    acc4.x = fmaf(wm2, v2.x, acc4.x);
    acc4.y = fmaf(wm2, v2.y, acc4.y);
    acc4.z = fmaf(wm2, v2.z, acc4.z);
    acc4.w = fmaf(wm2, v2.w, acc4.w);
    acc4.x = fmaf(wm3, v3.x, acc4.x);
    acc4.y = fmaf(wm3, v3.y, acc4.y);
    acc4.z = fmaf(wm3, v3.z, acc4.z);
    acc4.w = fmaf(wm3, v3.w, acc4.w);
  }
#pragma unroll
  for (int off = 16; off <= 32; off <<= 1) {
    acc4.x += __shfl_xor(acc4.x, off, 64);
    acc4.y += __shfl_xor(acc4.y, off, 64);
    acc4.z += __shfl_xor(acc4.z, off, 64);
    acc4.w += __shfl_xor(acc4.w, off, 64);
  }
  if (g == 0) {
    // fused gate + frag-global hi/lo store (replaces gate_mul kernel).
    const int c0 = (h << 6) + d4;
    const float4 gv = *(const float4*)(gate + ((size_t)qi << 10) + c0);
    float p[4] = {acc4.x * scale * gv.x, acc4.y * scale * gv.y,
                  acc4.z * scale * gv.z, acc4.w * scale * gv.w};
    unsigned short ph[4], pl[4];
#pragma unroll
    for (int jj = 0; jj < 4; ++jj) {
      unsigned short hb = bf16rn(p[jj]);
      ph[jj] = hb;
      pl[jj] = bf16rn(p[jj] - __uint_as_float((unsigned)hb << 16));
    }
    const int k8 = c0 >> 3;
    const int t16 = qi >> 4, rr = qi & 15, kc = k8 >> 2, kq = k8 & 3;
    const size_t elem = (((size_t)(t16 * 32 + kc)) * 64 + ((kq << 4) | rr)) * 8 + (d4 & 7);
    ushort4 vh4 = {ph[0], ph[1], ph[2], ph[3]};
    ushort4 vl4 = {pl[0], pl[1], pl[2], pl[3]};
    *(ushort4*)(Yh + elem) = vh4;
    *(ushort4*)(Yl + elem) = vl4;
  }
}

extern "C" void kernel_launch(void* const* d_in, const int* in_sizes, int n_in,
                              void* d_out, int out_size, void* d_ws, size_t ws_size,
                              hipStream_t stream) {
  (void)in_sizes; (void)n_in; (void)out_size; (void)ws_size;
  const float* x           = (const float*)d_in[0];
  const float* w_attn      = (const float*)d_in[1];
  const float* w_proj      = (const float*)d_in[2];
  const float* w_gate      = (const float*)d_in[3];
  const float* span_params = (const float*)d_in[4];
  float* out = (float*)d_out;

  char* ws = (char*)d_ws;
  const size_t MB = 1024 * 1024;
  float* q     = (float*)(ws);            // 8 MB (qfrag direct; P0 after attn)
  float* k     = (float*)(ws + 8 * MB);   // 8 MB (kfrag direct; P1 after attn)
  float* v     = (float*)(ws + 16 * MB);  // 8 MB
  float* gate  = (float*)(ws + 24 * MB);  // 8 MB
  unsigned short* xf_h  = (unsigned short*)(ws + 40 * MB);  // 4 MB
  unsigned short* xf_l  = (unsigned short*)(ws + 44 * MB);  // 4 MB
  unsigned short* wqg_h = (unsigned short*)(ws + 48 * MB);  // 8 MB
  unsigned short* wqg_l = (unsigned short*)(ws + 56 * MB);  // 8 MB
  unsigned short* wfp_h = (unsigned short*)(ws + 64 * MB);  // 2 MB
  unsigned short* wfp_l = (unsigned short*)(ws + 66 * MB);  // 2 MB
  unsigned short* ygf_h = (unsigned short*)(ws + 68 * MB);  // 4 MB
  unsigned short* ygf_l = (unsigned short*)(ws + 72 * MB);  // 4 MB
  float2* rope_tab = (float2*)(ws + 76 * MB);               // 0.5 MB
  float* P0 = q;   // dead after attn
  float* P1 = k;

  convert_all_kernel<<<3840, 256, 0, stream>>>(
      x, w_attn, w_gate, w_proj, xf_h, xf_l, wqg_h, wqg_l, wfp_h, wfp_l, rope_tab);
  mgemm_qkvg_kernel<<<dim3(32, 16), 512, 0, stream>>>(
      xf_h, xf_l, wqg_h, wqg_l, q, k, v, gate, rope_tab);
  attn_kernel<<<dim3(T_DIM / QTILE, H_DIM), 512, 0, stream>>>(
      q, k, v, span_params, gate, ygf_h, ygf_l);
  mgemm_proj_kernel<<<dim3(8, 32, 2), 256, 0, stream>>>(
      ygf_h, ygf_l, wfp_h, wfp_l, P0, P1);
  add2_kernel<<<(T_DIM * C_DIM) / 1024, 256, 0, stream>>>(P0, P1, out);
}